// Round 12
// baseline (150.320 us; speedup 1.0000x reference)
//
#include <hip/hip_runtime.h>
#include <hip/hip_bf16.h>

typedef short s16x8 __attribute__((ext_vector_type(8)));
typedef short s16x4 __attribute__((ext_vector_type(4)));
typedef float f32x4 __attribute__((ext_vector_type(4)));
typedef unsigned u32;
typedef u32 u32x2 __attribute__((ext_vector_type(2)));

#define DI __device__ __forceinline__

constexpr int BB = 16;    // batch
constexpr int CC = 256;   // in channels
constexpr int MM = 4096;  // H*W
constexpr int KD = 16;    // k
constexpr int UK = 64;    // u*k
constexpr float EPSV = 1e-5f;

DI unsigned short f2bf(float f) {
  union { float f; unsigned u; } v; v.f = f;
  unsigned r = v.u + 0x7FFFu + ((v.u >> 16) & 1u);
  return (unsigned short)(r >> 16);
}
DI float bfu(unsigned short u) { union { u32 u; float f; } w; w.u = (u32)u << 16; return w.f; }
DI float bflo(u32 v) { union { u32 u; float f; } w; w.u = v << 16; return w.f; }
DI float bfhi(u32 v) { union { u32 u; float f; } w; w.u = v & 0xFFFF0000u; return w.f; }

// ---- streaming convert x f32 -> bf16, per-(b,c) partial sum (no atomics) ----
__global__ __launch_bounds__(256) void k_cvt(const float* __restrict__ x,
    unsigned short* __restrict__ xbf, float* __restrict__ xsump) {
  int bid = blockIdx.x;                 // b*256 + c
  size_t base = (size_t)bid * MM;
  int t = threadIdx.x;
  float s = 0.f;
#pragma unroll
  for (int i = 0; i < 4; ++i) {
    size_t idx = base + (size_t)(i * 256 + t) * 4;
    float4 v = *(const float4*)(x + idx);
    s16x4 c;
    c[0] = (short)f2bf(v.x); c[1] = (short)f2bf(v.y);
    c[2] = (short)f2bf(v.z); c[3] = (short)f2bf(v.w);
    *(s16x4*)&xbf[idx] = c;
    s += v.x + v.y + v.z + v.w;
  }
#pragma unroll
  for (int o = 32; o; o >>= 1) s += __shfl_down(s, o);
  __shared__ float red[4];
  if ((t & 63) == 0) red[t >> 6] = s;
  __syncthreads();
  if (t == 0) xsump[bid] = red[0] + red[1] + red[2] + red[3];
}

// ---- G-partial = X_chunk X_chunk^T (bf16 MFMA, double-buffered LDS) ----
__global__ __launch_bounds__(512) void k_gxx(const unsigned short* __restrict__ xbf,
                                             u32* __restrict__ part) {
  int b = blockIdx.x >> 4, mc = blockIdx.x & 15;
  int m0 = mc * 256;
  __shared__ short lds[2][256 * 72];    // pitch 72 bf16 = 144B
  int t = threadIdx.x, w = t >> 6, l = t & 63;
  int wr = w >> 2, wc = w & 3;
  int lrow = l & 15, lk8 = (l >> 4) * 8;
  int srow = t >> 3, sseg = (t & 7) * 8;

  const unsigned short* gsrc = xbf + ((size_t)(b * CC + srow)) * MM + m0 + sseg;

  s16x8 rg[4];
#pragma unroll
  for (int i = 0; i < 4; ++i)
    rg[i] = *(const s16x8*)(gsrc + (size_t)i * 64 * MM);
#pragma unroll
  for (int i = 0; i < 4; ++i)
    *(s16x8*)&lds[0][(srow + i * 64) * 72 + sseg] = rg[i];

  f32x4 acc[8][4];
#pragma unroll
  for (int i = 0; i < 8; ++i)
#pragma unroll
    for (int j = 0; j < 4; ++j) acc[i][j] = (f32x4)0.f;

#pragma unroll
  for (int ks = 0; ks < 4; ++ks) {
    __syncthreads();
    if (ks < 3) {
#pragma unroll
      for (int i = 0; i < 4; ++i)
        rg[i] = *(const s16x8*)(gsrc + (size_t)i * 64 * MM + (ks + 1) * 64);
    }
    int buf = ks & 1;
#pragma unroll
    for (int half = 0; half < 2; ++half) {
      s16x8 af[8], bf[4];
#pragma unroll
      for (int i = 0; i < 8; ++i)
        af[i] = *(const s16x8*)&lds[buf][(wr * 128 + i * 16 + lrow) * 72 + half * 32 + lk8];
#pragma unroll
      for (int j = 0; j < 4; ++j)
        bf[j] = *(const s16x8*)&lds[buf][(wc * 64 + j * 16 + lrow) * 72 + half * 32 + lk8];
#pragma unroll
      for (int i = 0; i < 8; ++i)
#pragma unroll
        for (int j = 0; j < 4; ++j)
          acc[i][j] = __builtin_amdgcn_mfma_f32_16x16x32_bf16(af[i], bf[j], acc[i][j], 0, 0, 0);
    }
    if (ks < 3) {
#pragma unroll
      for (int i = 0; i < 4; ++i)
        *(s16x8*)&lds[buf ^ 1][(srow + i * 64) * 72 + sseg] = rg[i];
    }
  }

  size_t pb = (size_t)blockIdx.x * 32768;
#pragma unroll
  for (int i = 0; i < 8; ++i)
#pragma unroll
    for (int j = 0; j < 4; ++j) {
      int tau = (w * 8 + i) * 4 + j;
      u32x2 pk;
      pk[0] = (u32)f2bf(acc[i][j][0]) | ((u32)f2bf(acc[i][j][1]) << 16);
      pk[1] = (u32)f2bf(acc[i][j][2]) | ((u32)f2bf(acc[i][j][3]) << 16);
      *(u32x2*)&part[pb + tau * 128 + l * 2] = pk;
    }
}

// ---- reduce 256 G-partials -> G ----
__global__ __launch_bounds__(256) void k_gred(const u32* __restrict__ part,
                                              float* __restrict__ G) {
  int q = blockIdx.x * 256 + threadIdx.x;   // 0..32767
  float s0 = 0.f, s1 = 0.f;
#pragma unroll 8
  for (int p = 0; p < 256; ++p) {
    u32 v = part[(size_t)p * 32768 + q];
    s0 += bflo(v);
    s1 += bfhi(v);
  }
  int r2 = q & 1, l = (q >> 1) & 63, tau = q >> 7;
  int j = tau & 3, i = (tau >> 2) & 7, w = tau >> 5;
  int wr = w >> 2, wc = w & 3;
  int row = wr * 128 + i * 16 + (l >> 4) * 4 + r2 * 2;
  int col = wc * 64 + j * 16 + (l & 15);
  G[row * 256 + col] = s0;
  G[(row + 1) * 256 + col] = s1;
}

// ---- Q/K projection (bf16 MFMA) + fused softmax stats ----
// grid 1024 = 16 b x 64 m-chunks of 64; 4 waves, each 80o x 16m (acc[5][1]);
// dbuf W + x^T tiles, ONE barrier per K-step; ~21.5 KB LDS -> 4+ blocks/CU
__global__ __launch_bounds__(256) void k_proj(const unsigned short* __restrict__ xbf,
    const float* __restrict__ Wq, const float* __restrict__ bq,
    const float* __restrict__ Wk, const float* __restrict__ bk,
    unsigned short* __restrict__ Kbf, unsigned short* __restrict__ Qbf,
    float* __restrict__ pstat) {
  int b = blockIdx.x >> 6, mc = blockIdx.x & 63;   // 16 b * 64 m-chunks of 64
  int gm0 = mc * 64;
  __shared__ u32 xt[2][64 * 17];        // x^T tile (m-major, c-pair packed), 2x4.3 KB
  __shared__ short wb[2][80 * 40];      // W tile 80x32 bf16, pitch 40
  __shared__ float smax[4][64], ssum[4][64];
  int t = threadIdx.x;
  int w = t >> 6, l = t & 63;
  int lrow = l & 15, lk = l >> 4;
  int c2 = t >> 4;          // c-pair column 0..15
  int mq = t & 15;          // m quad index (m = mq*4..+3)
  int wrow0 = t >> 3;       // 0..31; reps add 32/64
  int wcol = (t & 7) * 4;   // 0..28

  s16x4 xv0, xv1;
  float4 wv[3];

  // prologue: load + stage ks=0 into buf 0
  {
    const unsigned short* p0 = xbf + ((size_t)(b * CC + 2 * c2)) * MM + gm0 + mq * 4;
    xv0 = *(const s16x4*)p0;
    xv1 = *(const s16x4*)(p0 + MM);
#pragma unroll
    for (int rep = 0; rep < 3; ++rep) {
      int row = rep * 32 + wrow0;
      if (row < 80)
        wv[rep] = *(const float4*)((row < 64 ? Wk + (size_t)row * CC
                                             : Wq + (size_t)(row - 64) * CC) + wcol);
    }
#pragma unroll
    for (int i = 0; i < 4; ++i)
      xt[0][(mq * 4 + i) * 17 + c2] =
          (u32)(unsigned short)xv0[i] | ((u32)(unsigned short)xv1[i] << 16);
#pragma unroll
    for (int rep = 0; rep < 3; ++rep) {
      int row = rep * 32 + wrow0;
      if (row < 80) {
        s16x4 wc4;
        wc4[0] = (short)f2bf(wv[rep].x); wc4[1] = (short)f2bf(wv[rep].y);
        wc4[2] = (short)f2bf(wv[rep].z); wc4[3] = (short)f2bf(wv[rep].w);
        *(s16x4*)&wb[0][row * 40 + wcol] = wc4;
      }
    }
  }
  __syncthreads();

  f32x4 acc[5];
#pragma unroll
  for (int i = 0; i < 5; ++i) acc[i] = (f32x4)0.f;

  for (int ks = 0; ks < 8; ++ks) {
    int buf = ks & 1;
    if (ks < 7) {   // issue next-step global loads early
      int c0 = (ks + 1) * 32;
      const unsigned short* p0 = xbf + ((size_t)(b * CC + c0 + 2 * c2)) * MM + gm0 + mq * 4;
      xv0 = *(const s16x4*)p0;
      xv1 = *(const s16x4*)(p0 + MM);
#pragma unroll
      for (int rep = 0; rep < 3; ++rep) {
        int row = rep * 32 + wrow0;
        if (row < 80)
          wv[rep] = *(const float4*)((row < 64 ? Wk + (size_t)row * CC
                                               : Wq + (size_t)(row - 64) * CC) + c0 + wcol);
      }
    }
    // frag reads + MFMA from buf
    union { s16x8 v; u32 wd[4]; } bfr;
    int ml = w * 16 + lrow;
#pragma unroll
    for (int i = 0; i < 4; ++i) bfr.wd[i] = xt[buf][ml * 17 + lk * 4 + i];
#pragma unroll
    for (int ot = 0; ot < 5; ++ot) {
      s16x8 af = *(const s16x8*)&wb[buf][(ot * 16 + lrow) * 40 + lk * 8];
      acc[ot] = __builtin_amdgcn_mfma_f32_16x16x32_bf16(af, bfr.v, acc[ot], 0, 0, 0);
    }
    if (ks < 7) {   // write-late into the other buffer
#pragma unroll
      for (int i = 0; i < 4; ++i)
        xt[buf ^ 1][(mq * 4 + i) * 17 + c2] =
            (u32)(unsigned short)xv0[i] | ((u32)(unsigned short)xv1[i] << 16);
#pragma unroll
      for (int rep = 0; rep < 3; ++rep) {
        int row = rep * 32 + wrow0;
        if (row < 80) {
          s16x4 wc4;
          wc4[0] = (short)f2bf(wv[rep].x); wc4[1] = (short)f2bf(wv[rep].y);
          wc4[2] = (short)f2bf(wv[rep].z); wc4[3] = (short)f2bf(wv[rep].w);
          *(s16x4*)&wb[buf ^ 1][row * 40 + wcol] = wc4;
        }
      }
    }
    __syncthreads();
  }

  int mcol = gm0 + w * 16 + lrow;
#pragma unroll
  for (int ot = 0; ot < 4; ++ot)
#pragma unroll
    for (int r = 0; r < 4; ++r) {
      int o = ot * 16 + lk * 4 + r;
      float bias = bk[o];
      unsigned short u0 = f2bf(acc[ot][r] + bias);
      Kbf[((size_t)(b * UK + o)) * MM + mcol] = u0;
      float rv0 = bfu(u0);
      float mx = rv0;
      mx = fmaxf(mx, __shfl_xor(mx, 1));
      mx = fmaxf(mx, __shfl_xor(mx, 2));
      mx = fmaxf(mx, __shfl_xor(mx, 4));
      mx = fmaxf(mx, __shfl_xor(mx, 8));
      float se = __expf(rv0 - mx);
      se += __shfl_xor(se, 1);
      se += __shfl_xor(se, 2);
      se += __shfl_xor(se, 4);
      se += __shfl_xor(se, 8);
      if (lrow == 0) { smax[w][o] = mx; ssum[w][o] = se; }
    }
#pragma unroll
  for (int r = 0; r < 4; ++r) {
    int oq = lk * 4 + r;
    Qbf[((size_t)(b * KD + oq)) * MM + mcol] = f2bf(acc[4][r] + bq[oq]);
  }
  __syncthreads();
  if (t < 64) {
    float m0_ = smax[0][t], m1_ = smax[1][t], m2_ = smax[2][t], m3_ = smax[3][t];
    float mm = fmaxf(fmaxf(m0_, m1_), fmaxf(m2_, m3_));
    float ss = ssum[0][t] * __expf(m0_ - mm) + ssum[1][t] * __expf(m1_ - mm) +
               ssum[2][t] * __expf(m2_ - mm) + ssum[3][t] * __expf(m3_ - mm);
    size_t po = ((size_t)blockIdx.x * 64 + t) * 2;
    pstat[po] = mm;
    pstat[po + 1] = ss;
  }
}

// ---- merge 64 per-block stats -> rmax, rsum (online-softmax merge) ----
__global__ __launch_bounds__(64) void k_pmerge(const float* __restrict__ pstat,
    float* __restrict__ rmax, float* __restrict__ rsum) {
  int b = blockIdx.x, o = threadIdx.x;
  float mm = -3.4e38f;
#pragma unroll 8
  for (int mc = 0; mc < 64; ++mc)
    mm = fmaxf(mm, pstat[((size_t)((b * 64 + mc) * 64 + o)) * 2]);
  float ss = 0.f;
#pragma unroll 8
  for (int mc = 0; mc < 64; ++mc) {
    size_t po = ((size_t)((b * 64 + mc) * 64 + o)) * 2;
    ss += pstat[po + 1] * __expf(pstat[po] - mm);
  }
  rmax[b * 64 + o] = mm;
  rsum[b * 64 + o] = ss;
}

// ---- BN affine params: 4 channels/block, coalesced row-streamed G ----
__global__ __launch_bounds__(256) void k_fin(const float* __restrict__ G,
    const float* __restrict__ xsump,
    const float* __restrict__ Wv, const float* __restrict__ bv,
    const float* __restrict__ gv, const float* __restrict__ btv,
    const float* __restrict__ Wq, const float* __restrict__ bq,
    const float* __restrict__ gq, const float* __restrict__ btq,
    float* __restrict__ AV, float* __restrict__ BVa,
    float* __restrict__ AQ, float* __restrict__ BQa) {
  int t = threadIdx.x, w = t >> 6, l = t & 63;
  int o0 = blockIdx.x * 4;
  __shared__ float lw[4][256];
#pragma unroll
  for (int oo = 0; oo < 4; ++oo) {
    int o = o0 + oo;
    lw[oo][t] = (o < 1024) ? Wv[(size_t)o * CC + t] : Wq[(size_t)(o - 1024) * CC + t];
  }
  __syncthreads();

  float4 w4[4];
#pragma unroll
  for (int oo = 0; oo < 4; ++oo) w4[oo] = *(const float4*)&lw[oo][4 * l];

  float qf[4] = {0.f, 0.f, 0.f, 0.f};
#pragma unroll 4
  for (int i = 0; i < 64; ++i) {
    int r = i * 4 + w;
    float4 g4 = *(const float4*)(G + (size_t)r * CC + 4 * l);
#pragma unroll
    for (int oo = 0; oo < 4; ++oo) {
      float d = g4.x * w4[oo].x + g4.y * w4[oo].y + g4.z * w4[oo].z + g4.w * w4[oo].w;
      qf[oo] = fmaf(lw[oo][r], d, qf[oo]);
    }
  }

  float xs = 0.f;
#pragma unroll
  for (int bb = 0; bb < 16; ++bb) xs += xsump[bb * 256 + t];
  float sx[4];
#pragma unroll
  for (int oo = 0; oo < 4; ++oo) sx[oo] = lw[oo][t] * xs;

#pragma unroll
  for (int oo = 0; oo < 4; ++oo)
#pragma unroll
    for (int od = 32; od; od >>= 1) {
      qf[oo] += __shfl_xor(qf[oo], od);
      sx[oo] += __shfl_xor(sx[oo], od);
    }
  __shared__ float rq[4][4], rs[4][4];
  if (l == 0)
#pragma unroll
    for (int oo = 0; oo < 4; ++oo) { rq[w][oo] = qf[oo]; rs[w][oo] = sx[oo]; }
  __syncthreads();
  if (t < 4) {
    int oo = t, o = o0 + oo;
    float q = rq[0][oo] + rq[1][oo] + rq[2][oo] + rq[3][oo];
    float s = rs[0][oo] + rs[1][oo] + rs[2][oo] + rs[3][oo];
    float bias, gamma, beta; float *pa, *pb;
    if (o < 1024) { bias = bv[o]; gamma = gv[o]; beta = btv[o]; pa = AV + o; pb = BVa + o; }
    else { int oi = o - 1024; bias = bq[oi]; gamma = gq[oi]; beta = btq[oi]; pa = AQ + oi; pb = BQa + oi; }
    const float invN = 1.f / 65536.f;
    float mean = s * invN + bias;
    float e2 = q * invN + 2.f * bias * s * invN + bias * bias;
    float var = e2 - mean * mean;
    float a = gamma * rsqrtf(var + EPSV);
    *pa = a;
    *pb = beta - mean * a;
  }
}

// ---- xp-partial = exp(K-rmax) . x^T  (dbuf LDS, one barrier per K-step) ----
__global__ __launch_bounds__(256) void k_xp(const unsigned short* __restrict__ xbf,
    const unsigned short* __restrict__ Kbf, const float* __restrict__ rmax,
    float* __restrict__ xpp) {
  int b = blockIdx.x >> 4, kc = blockIdx.x & 15;
  int kbase = kc * 256;
  __shared__ short la[2][64 * 40];
  __shared__ short lb[2][256 * 40];
  int t = threadIdx.x, w = t >> 6, l = t & 63;
  int lrow = l & 15, lk = (l >> 4) * 8;
  int ra = t >> 2, sga = (t & 3) * 8;    // A staging: row 0..63, seg 0..24

  float rm = rmax[b * UK + ra];
  const unsigned short* ksrc = Kbf + ((size_t)(b * UK + ra)) * MM + kbase + sga;
  const unsigned short* xsrc = xbf + ((size_t)(b * CC + ra)) * MM + kbase + sga;

  s16x8 kv, xv[4];

  // prologue: ks=0 loads + stage into buf 0
  kv = *(const s16x8*)ksrc;
#pragma unroll
  for (int i = 0; i < 4; ++i)
    xv[i] = *(const s16x8*)(xsrc + (size_t)i * 64 * MM);
  {
    s16x8 ev;
#pragma unroll
    for (int i = 0; i < 8; ++i)
      ev[i] = (short)f2bf(__expf(bfu((unsigned short)kv[i]) - rm));
    *(s16x8*)&la[0][ra * 40 + sga] = ev;
#pragma unroll
    for (int i = 0; i < 4; ++i)
      *(s16x8*)&lb[0][(ra + i * 64) * 40 + sga] = xv[i];
  }
  __syncthreads();

  f32x4 acc[4][4];
#pragma unroll
  for (int i = 0; i < 4; ++i)
#pragma unroll
    for (int j = 0; j < 4; ++j) acc[i][j] = (f32x4)0.f;

  for (int ks = 0; ks < 8; ++ks) {
    int buf = ks & 1;
    if (ks < 7) {   // issue next-step global loads early
      int k1 = (ks + 1) * 32;
      kv = *(const s16x8*)(ksrc + k1);
#pragma unroll
      for (int i = 0; i < 4; ++i)
        xv[i] = *(const s16x8*)(xsrc + (size_t)i * 64 * MM + k1);
    }
    s16x8 af[4], bfr[4];
#pragma unroll
    for (int i = 0; i < 4; ++i) af[i] = *(const s16x8*)&la[buf][(i * 16 + lrow) * 40 + lk];
#pragma unroll
    for (int j = 0; j < 4; ++j) bfr[j] = *(const s16x8*)&lb[buf][(w * 64 + j * 16 + lrow) * 40 + lk];
#pragma unroll
    for (int i = 0; i < 4; ++i)
#pragma unroll
      for (int j = 0; j < 4; ++j)
        acc[i][j] = __builtin_amdgcn_mfma_f32_16x16x32_bf16(af[i], bfr[j], acc[i][j], 0, 0, 0);
    if (ks < 7) {   // convert + write-late into the other buffer
      s16x8 ev;
#pragma unroll
      for (int i = 0; i < 8; ++i)
        ev[i] = (short)f2bf(__expf(bfu((unsigned short)kv[i]) - rm));
      *(s16x8*)&la[buf ^ 1][ra * 40 + sga] = ev;
#pragma unroll
      for (int i = 0; i < 4; ++i)
        *(s16x8*)&lb[buf ^ 1][(ra + i * 64) * 40 + sga] = xv[i];
    }
    __syncthreads();
  }

  float* dst = xpp + (size_t)blockIdx.x * UK * CC;
#pragma unroll
  for (int i = 0; i < 4; ++i)
#pragma unroll
    for (int j = 0; j < 4; ++j)
#pragma unroll
      for (int r = 0; r < 4; ++r) {
        int row = i * 16 + (l >> 4) * 4 + r;
        int col = w * 64 + j * 16 + lrow;
        dst[row * 256 + col] = acc[i][j][r];
      }
}

// ---- prep: xpn (reduce+normalize+bf16) and wvs (AV-scaled Wv, bf16), one launch ----
__global__ __launch_bounds__(256) void k_prep(const float* __restrict__ xpp,
    const float* __restrict__ rsum, const float* __restrict__ Wv,
    const float* __restrict__ AV, unsigned short* __restrict__ xpn,
    unsigned short* __restrict__ wvs) {
  int t = threadIdx.x;
  if (blockIdx.x < 256) {
    int b = blockIdx.x >> 4, kk = blockIdx.x & 15;
    unsigned short* dst = xpn + ((size_t)(b * 16 + kk)) * 1024;
#pragma unroll
    for (int u = 0; u < 4; ++u) {
      int row = u * 16 + kk;
      float s = 0.f;
#pragma unroll
      for (int kc = 0; kc < 16; ++kc)
        s += xpp[((size_t)(b * 16 + kc) * UK + row) * CC + t];
      s /= rsum[b * UK + row];
      dst[u * 256 + t] = f2bf(s);
    }
  } else {
    int ch = blockIdx.x - 256;   // 0..1023
    float a = AV[ch];
    wvs[(size_t)ch * CC + t] = f2bf(a * Wv[(size_t)ch * CC + t]);
  }
}

// ---- ctx[(b,kk)][vv] = xpn . wvs^T + cst[vv]  (MFMA, M=N=256, K=1024) ----
__global__ __launch_bounds__(64) void k_ctx2(const unsigned short* __restrict__ xpn,
    const unsigned short* __restrict__ wvs,
    const float* __restrict__ AV, const float* __restrict__ bv,
    const float* __restrict__ BVa, float* __restrict__ CTX) {
  int mt = blockIdx.x >> 3, nt = blockIdx.x & 7;
  int m0 = mt * 32, n0 = nt * 32;
  int l = threadIdx.x;
  int lrow = l & 15, lk8 = (l >> 4) * 8;

  f32x4 acc[2][2];
#pragma unroll
  for (int i = 0; i < 2; ++i)
#pragma unroll
    for (int j = 0; j < 2; ++j) acc[i][j] = (f32x4)0.f;

#pragma unroll 4
  for (int k0 = 0; k0 < 1024; k0 += 32) {
    int u = k0 >> 8, c0 = k0 & 255;
    s16x8 a0 = *(const s16x8*)&xpn[(size_t)(m0 + lrow) * 1024 + k0 + lk8];
    s16x8 a1 = *(const s16x8*)&xpn[(size_t)(m0 + 16 + lrow) * 1024 + k0 + lk8];
    s16x8 b0 = *(const s16x8*)&wvs[(size_t)(u * 256 + n0 + lrow) * CC + c0 + lk8];
    s16x8 b1 = *(const s16x8*)&wvs[(size_t)(u * 256 + n0 + 16 + lrow) * CC + c0 + lk8];
    acc[0][0] = __builtin_amdgcn_mfma_f32_16x16x32_bf16(a0, b0, acc[0][0], 0, 0, 0);
    acc[0][1] = __builtin_amdgcn_mfma_f32_16x16x32_bf16(a0, b1, acc[0][1], 0, 0, 0);
    acc[1][0] = __builtin_amdgcn_mfma_f32_16x16x32_bf16(a1, b0, acc[1][0], 0, 0, 0);
    acc[1][1] = __builtin_amdgcn_mfma_f32_16x16x32_bf16(a1, b1, acc[1][1], 0, 0, 0);
  }

  float cst[2];
#pragma unroll
  for (int j = 0; j < 2; ++j) {
    int vv = n0 + j * 16 + lrow;
    float s = 0.f;
#pragma unroll
    for (int u = 0; u < 4; ++u) {
      int ch = u * 256 + vv;
      s += AV[ch] * bv[ch] + BVa[ch];
    }
    cst[j] = s;
  }

#pragma unroll
  for (int i = 0; i < 2; ++i)
#pragma unroll
    for (int j = 0; j < 2; ++j)
#pragma unroll
      for (int r = 0; r < 4; ++r) {
        int row = m0 + i * 16 + (l >> 4) * 4 + r;
        int col = n0 + j * 16 + lrow;
        CTX[(size_t)row * 256 + col] = acc[i][j][r] + cst[j];
      }
}

// ---- y[b,vv,m] = sum_kk (aQ*Q+bQ)[kk,m] * ctx[kk,vv]  (bf16 Q input) ----
__global__ __launch_bounds__(256) void k_y(const unsigned short* __restrict__ Qbf,
    const float* __restrict__ CTX,
    const float* __restrict__ AQ, const float* __restrict__ BQa,
    float* __restrict__ y) {
  int b = blockIdx.x >> 4, nc = blockIdx.x & 15;
  int m = nc * 256 + threadIdx.x;
  float qn[16];
#pragma unroll
  for (int kk = 0; kk < 16; ++kk)
    qn[kk] = AQ[kk] * bfu(Qbf[((size_t)b * KD + kk) * MM + m]) + BQa[kk];
  const float* cb = CTX + (size_t)b * KD * 256;
  float* yo = y + (size_t)b * 256 * MM + m;
#pragma unroll 4
  for (int vv = 0; vv < 256; ++vv) {
    float acc = 0.f;
#pragma unroll
    for (int kk = 0; kk < 16; ++kk)
      acc = fmaf(qn[kk], cb[kk * 256 + vv], acc);
    yo[(size_t)vv * MM] = acc;
  }
}

extern "C" void kernel_launch(void* const* d_in, const int* in_sizes, int n_in,
                              void* d_out, int out_size, void* d_ws, size_t ws_size,
                              hipStream_t stream) {
  const float* x   = (const float*)d_in[0];
  const float* Wq  = (const float*)d_in[1];
  const float* bq  = (const float*)d_in[2];
  const float* Wk  = (const float*)d_in[3];
  const float* bk  = (const float*)d_in[4];
  const float* Wv  = (const float*)d_in[5];
  const float* bv  = (const float*)d_in[6];
  const float* gq  = (const float*)d_in[7];
  const float* btq = (const float*)d_in[8];
  const float* gv  = (const float*)d_in[9];
  const float* btv = (const float*)d_in[10];
  float* out = (float*)d_out;
  float* ws  = (float*)d_ws;

  // workspace layout (f32-element offsets) — no zero-init required anywhere
  float* G     = ws;                      // 65536     -> 65536
  float* XSUMP = ws + 65536;              // 4096      -> 69632
  float* PSTAT = ws + 69632;              // 131072    -> 200704 (1024 blocks x 64 x 2)
  float* RMAX  = ws + 200704;             // 1024      -> 201728
  float* RSUM  = ws + 201728;             // 1024      -> 202752
  float* AV    = ws + 202752;             // 1024      -> 203776
  float* BVa   = ws + 203776;             // 1024      -> 204800
  float* AQ    = ws + 204800;             // 16        -> 204816
  float* BQa   = ws + 204816;             // 16 (pad)  -> 205056
  float* CTX   = ws + 205056;             // 65536     -> 270592
  u32*  PART   = (u32*)(ws + 270592);     // 8388608 u32 -> f32-elem 8659200 (dead after k_gred)
  float* XPP   = ws + 270592;             // 4194304   -> 4464896 (aliases PART)
  unsigned short* KBf = (unsigned short*)(ws + 4464896); // 4194304 bf16 -> 6562048 (aliases PART)
  unsigned short* QBf = (unsigned short*)(ws + 6562048); // 1048576 bf16 -> 7086336 (aliases PART)
  unsigned short* XBF = (unsigned short*)(ws + 8659200); // 16777216 bf16 -> 17047808
  unsigned short* XPN = (unsigned short*)(ws + 17047808); // 262144 bf16 -> 17178880
  unsigned short* WVS = (unsigned short*)(ws + 17178880); // 262144 bf16 -> 17309952 (~69.2 MB)

  k_cvt   <<<4096, 256, 0, stream>>>(x, XBF, XSUMP);
  k_gxx   <<<256,  512, 0, stream>>>(XBF, PART);
  k_gred  <<<128,  256, 0, stream>>>(PART, G);
  k_proj  <<<1024, 256, 0, stream>>>(XBF, Wq, bq, Wk, bk, KBf, QBf, PSTAT);
  k_pmerge<<<16,   64,  0, stream>>>(PSTAT, RMAX, RSUM);
  k_fin   <<<260,  256, 0, stream>>>(G, XSUMP, Wv, bv, gv, btv, Wq, bq, gq, btq,
                                     AV, BVa, AQ, BQa);
  k_xp    <<<256,  256, 0, stream>>>(XBF, KBf, RMAX, XPP);
  k_prep  <<<1280, 256, 0, stream>>>(XPP, RSUM, Wv, AV, XPN, WVS);
  k_ctx2  <<<64,   64,  0, stream>>>(XPN, WVS, AV, bv, BVa, CTX);
  k_y     <<<256,  256, 0, stream>>>(QBf, CTX, AQ, BQa, out);
}

// Round 13
// 143.090 us; speedup vs baseline: 1.0505x; 1.0505x over previous
//
#include <hip/hip_runtime.h>
#include <hip/hip_bf16.h>

typedef short s16x8 __attribute__((ext_vector_type(8)));
typedef short s16x4 __attribute__((ext_vector_type(4)));
typedef float f32x4 __attribute__((ext_vector_type(4)));
typedef unsigned u32;
typedef u32 u32x2 __attribute__((ext_vector_type(2)));

#define DI __device__ __forceinline__

constexpr int BB = 16;    // batch
constexpr int CC = 256;   // in channels
constexpr int MM = 4096;  // H*W
constexpr int KD = 16;    // k
constexpr int UK = 64;    // u*k
constexpr float EPSV = 1e-5f;

DI unsigned short f2bf(float f) {
  union { float f; unsigned u; } v; v.f = f;
  unsigned r = v.u + 0x7FFFu + ((v.u >> 16) & 1u);
  return (unsigned short)(r >> 16);
}
DI float bfu(unsigned short u) { union { u32 u; float f; } w; w.u = (u32)u << 16; return w.f; }
DI float bflo(u32 v) { union { u32 u; float f; } w; w.u = v << 16; return w.f; }
DI float bfhi(u32 v) { union { u32 u; float f; } w; w.u = v & 0xFFFF0000u; return w.f; }

// ---- streaming convert x f32 -> bf16, per-(b,c) partial sum (no atomics) ----
__global__ __launch_bounds__(256) void k_cvt(const float* __restrict__ x,
    unsigned short* __restrict__ xbf, float* __restrict__ xsump) {
  int bid = blockIdx.x;                 // b*256 + c
  size_t base = (size_t)bid * MM;
  int t = threadIdx.x;
  float s = 0.f;
#pragma unroll
  for (int i = 0; i < 4; ++i) {
    size_t idx = base + (size_t)(i * 256 + t) * 4;
    float4 v = *(const float4*)(x + idx);
    s16x4 c;
    c[0] = (short)f2bf(v.x); c[1] = (short)f2bf(v.y);
    c[2] = (short)f2bf(v.z); c[3] = (short)f2bf(v.w);
    *(s16x4*)&xbf[idx] = c;
    s += v.x + v.y + v.z + v.w;
  }
#pragma unroll
  for (int o = 32; o; o >>= 1) s += __shfl_down(s, o);
  __shared__ float red[4];
  if ((t & 63) == 0) red[t >> 6] = s;
  __syncthreads();
  if (t == 0) xsump[bid] = red[0] + red[1] + red[2] + red[3];
}

// ---- G-partial = X_chunk X_chunk^T (bf16 MFMA, double-buffered LDS) ----
__global__ __launch_bounds__(512) void k_gxx(const unsigned short* __restrict__ xbf,
                                             u32* __restrict__ part) {
  int b = blockIdx.x >> 4, mc = blockIdx.x & 15;
  int m0 = mc * 256;
  __shared__ short lds[2][256 * 72];    // pitch 72 bf16 = 144B
  int t = threadIdx.x, w = t >> 6, l = t & 63;
  int wr = w >> 2, wc = w & 3;
  int lrow = l & 15, lk8 = (l >> 4) * 8;
  int srow = t >> 3, sseg = (t & 7) * 8;

  const unsigned short* gsrc = xbf + ((size_t)(b * CC + srow)) * MM + m0 + sseg;

  s16x8 rg[4];
#pragma unroll
  for (int i = 0; i < 4; ++i)
    rg[i] = *(const s16x8*)(gsrc + (size_t)i * 64 * MM);
#pragma unroll
  for (int i = 0; i < 4; ++i)
    *(s16x8*)&lds[0][(srow + i * 64) * 72 + sseg] = rg[i];

  f32x4 acc[8][4];
#pragma unroll
  for (int i = 0; i < 8; ++i)
#pragma unroll
    for (int j = 0; j < 4; ++j) acc[i][j] = (f32x4)0.f;

#pragma unroll
  for (int ks = 0; ks < 4; ++ks) {
    __syncthreads();
    if (ks < 3) {
#pragma unroll
      for (int i = 0; i < 4; ++i)
        rg[i] = *(const s16x8*)(gsrc + (size_t)i * 64 * MM + (ks + 1) * 64);
    }
    int buf = ks & 1;
#pragma unroll
    for (int half = 0; half < 2; ++half) {
      s16x8 af[8], bf[4];
#pragma unroll
      for (int i = 0; i < 8; ++i)
        af[i] = *(const s16x8*)&lds[buf][(wr * 128 + i * 16 + lrow) * 72 + half * 32 + lk8];
#pragma unroll
      for (int j = 0; j < 4; ++j)
        bf[j] = *(const s16x8*)&lds[buf][(wc * 64 + j * 16 + lrow) * 72 + half * 32 + lk8];
#pragma unroll
      for (int i = 0; i < 8; ++i)
#pragma unroll
        for (int j = 0; j < 4; ++j)
          acc[i][j] = __builtin_amdgcn_mfma_f32_16x16x32_bf16(af[i], bf[j], acc[i][j], 0, 0, 0);
    }
    if (ks < 3) {
#pragma unroll
      for (int i = 0; i < 4; ++i)
        *(s16x8*)&lds[buf ^ 1][(srow + i * 64) * 72 + sseg] = rg[i];
    }
  }

  size_t pb = (size_t)blockIdx.x * 32768;
#pragma unroll
  for (int i = 0; i < 8; ++i)
#pragma unroll
    for (int j = 0; j < 4; ++j) {
      int tau = (w * 8 + i) * 4 + j;
      u32x2 pk;
      pk[0] = (u32)f2bf(acc[i][j][0]) | ((u32)f2bf(acc[i][j][1]) << 16);
      pk[1] = (u32)f2bf(acc[i][j][2]) | ((u32)f2bf(acc[i][j][3]) << 16);
      *(u32x2*)&part[pb + tau * 128 + l * 2] = pk;
    }
}

// ---- reduce 256 G-partials -> G ----
__global__ __launch_bounds__(256) void k_gred(const u32* __restrict__ part,
                                              float* __restrict__ G) {
  int q = blockIdx.x * 256 + threadIdx.x;   // 0..32767
  float s0 = 0.f, s1 = 0.f;
#pragma unroll 8
  for (int p = 0; p < 256; ++p) {
    u32 v = part[(size_t)p * 32768 + q];
    s0 += bflo(v);
    s1 += bfhi(v);
  }
  int r2 = q & 1, l = (q >> 1) & 63, tau = q >> 7;
  int j = tau & 3, i = (tau >> 2) & 7, w = tau >> 5;
  int wr = w >> 2, wc = w & 3;
  int row = wr * 128 + i * 16 + (l >> 4) * 4 + r2 * 2;
  int col = wc * 64 + j * 16 + (l & 15);
  G[row * 256 + col] = s0;
  G[(row + 1) * 256 + col] = s1;
}

// ---- Q/K projection (bf16 MFMA) + fused softmax stats ----
// grid 512; per-step double-buffered W tile (80x32) + x^T tile; ONE barrier per K-step
__global__ __launch_bounds__(256) void k_proj(const unsigned short* __restrict__ xbf,
    const float* __restrict__ Wq, const float* __restrict__ bq,
    const float* __restrict__ Wk, const float* __restrict__ bk,
    unsigned short* __restrict__ Kbf, unsigned short* __restrict__ Qbf,
    float* __restrict__ pstat) {
  int b = blockIdx.x >> 5, mc = blockIdx.x & 31;   // 16 b * 32 m-chunks of 128
  int gm0 = mc * 128;
  __shared__ u32 xt[2][128 * 17];       // x^T tile (m-major, c-pair packed)
  __shared__ short wb[2][80 * 40];      // W tile 80x32 bf16, pitch 40
  __shared__ float smax[4][64], ssum[4][64];
  int t = threadIdx.x;
  int w = t >> 6, l = t & 63;
  int lrow = l & 15, lk = l >> 4;
  int c2 = t >> 4;          // c-pair column 0..15
  int mq = t & 15;          // m quad index
  int wrow0 = t >> 3;       // 0..31; reps add 32/64
  int wcol = (t & 7) * 4;   // 0..28

  s16x4 xv[2][2];
  float4 wv[3];

  // prologue: load + stage ks=0 into buf 0
  {
    const unsigned short* p0 = xbf + ((size_t)(b * CC + 2 * c2)) * MM + gm0 + mq * 4;
#pragma unroll
    for (int mb = 0; mb < 2; ++mb) {
      xv[mb][0] = *(const s16x4*)(p0 + mb * 64);
      xv[mb][1] = *(const s16x4*)(p0 + mb * 64 + MM);
    }
#pragma unroll
    for (int rep = 0; rep < 3; ++rep) {
      int row = rep * 32 + wrow0;
      if (row < 80)
        wv[rep] = *(const float4*)((row < 64 ? Wk + (size_t)row * CC
                                             : Wq + (size_t)(row - 64) * CC) + wcol);
    }
#pragma unroll
    for (int mb = 0; mb < 2; ++mb) {
      int m = mb * 64 + mq * 4;
#pragma unroll
      for (int i = 0; i < 4; ++i)
        xt[0][(m + i) * 17 + c2] =
            (u32)(unsigned short)xv[mb][0][i] | ((u32)(unsigned short)xv[mb][1][i] << 16);
    }
#pragma unroll
    for (int rep = 0; rep < 3; ++rep) {
      int row = rep * 32 + wrow0;
      if (row < 80) {
        s16x4 wc4;
        wc4[0] = (short)f2bf(wv[rep].x); wc4[1] = (short)f2bf(wv[rep].y);
        wc4[2] = (short)f2bf(wv[rep].z); wc4[3] = (short)f2bf(wv[rep].w);
        *(s16x4*)&wb[0][row * 40 + wcol] = wc4;
      }
    }
  }
  __syncthreads();

  f32x4 acc[5][2];
#pragma unroll
  for (int i = 0; i < 5; ++i) { acc[i][0] = (f32x4)0.f; acc[i][1] = (f32x4)0.f; }

  for (int ks = 0; ks < 8; ++ks) {
    int buf = ks & 1;
    if (ks < 7) {   // issue next-step global loads early
      int c0 = (ks + 1) * 32;
      const unsigned short* p0 = xbf + ((size_t)(b * CC + c0 + 2 * c2)) * MM + gm0 + mq * 4;
#pragma unroll
      for (int mb = 0; mb < 2; ++mb) {
        xv[mb][0] = *(const s16x4*)(p0 + mb * 64);
        xv[mb][1] = *(const s16x4*)(p0 + mb * 64 + MM);
      }
#pragma unroll
      for (int rep = 0; rep < 3; ++rep) {
        int row = rep * 32 + wrow0;
        if (row < 80)
          wv[rep] = *(const float4*)((row < 64 ? Wk + (size_t)row * CC
                                               : Wq + (size_t)(row - 64) * CC) + c0 + wcol);
      }
    }
    // frag reads + MFMA from buf
    union { s16x8 v; u32 wd[4]; } bfr[2];
#pragma unroll
    for (int j = 0; j < 2; ++j) {
      int ml = w * 32 + j * 16 + lrow;
#pragma unroll
      for (int i = 0; i < 4; ++i) bfr[j].wd[i] = xt[buf][ml * 17 + lk * 4 + i];
    }
#pragma unroll
    for (int ot = 0; ot < 5; ++ot) {
      s16x8 af = *(const s16x8*)&wb[buf][(ot * 16 + lrow) * 40 + lk * 8];
      acc[ot][0] = __builtin_amdgcn_mfma_f32_16x16x32_bf16(af, bfr[0].v, acc[ot][0], 0, 0, 0);
      acc[ot][1] = __builtin_amdgcn_mfma_f32_16x16x32_bf16(af, bfr[1].v, acc[ot][1], 0, 0, 0);
    }
    if (ks < 7) {   // write-late into the other buffer
#pragma unroll
      for (int mb = 0; mb < 2; ++mb) {
        int m = mb * 64 + mq * 4;
#pragma unroll
        for (int i = 0; i < 4; ++i)
          xt[buf ^ 1][(m + i) * 17 + c2] =
              (u32)(unsigned short)xv[mb][0][i] | ((u32)(unsigned short)xv[mb][1][i] << 16);
      }
#pragma unroll
      for (int rep = 0; rep < 3; ++rep) {
        int row = rep * 32 + wrow0;
        if (row < 80) {
          s16x4 wc4;
          wc4[0] = (short)f2bf(wv[rep].x); wc4[1] = (short)f2bf(wv[rep].y);
          wc4[2] = (short)f2bf(wv[rep].z); wc4[3] = (short)f2bf(wv[rep].w);
          *(s16x4*)&wb[buf ^ 1][row * 40 + wcol] = wc4;
        }
      }
    }
    __syncthreads();
  }

  int mcol = gm0 + w * 32 + lrow;
#pragma unroll
  for (int ot = 0; ot < 4; ++ot)
#pragma unroll
    for (int r = 0; r < 4; ++r) {
      int o = ot * 16 + lk * 4 + r;
      float bias = bk[o];
      unsigned short u0 = f2bf(acc[ot][0][r] + bias);
      unsigned short u1 = f2bf(acc[ot][1][r] + bias);
      size_t rowoff = ((size_t)(b * UK + o)) * MM;
      Kbf[rowoff + mcol] = u0;
      Kbf[rowoff + mcol + 16] = u1;
      float rv0 = bfu(u0), rv1 = bfu(u1);
      float mx = fmaxf(rv0, rv1);
      mx = fmaxf(mx, __shfl_xor(mx, 1));
      mx = fmaxf(mx, __shfl_xor(mx, 2));
      mx = fmaxf(mx, __shfl_xor(mx, 4));
      mx = fmaxf(mx, __shfl_xor(mx, 8));
      float se = __expf(rv0 - mx) + __expf(rv1 - mx);
      se += __shfl_xor(se, 1);
      se += __shfl_xor(se, 2);
      se += __shfl_xor(se, 4);
      se += __shfl_xor(se, 8);
      if (lrow == 0) { smax[w][o] = mx; ssum[w][o] = se; }
    }
#pragma unroll
  for (int r = 0; r < 4; ++r) {
    int oq = lk * 4 + r;
    float bias = bq[oq];
    size_t rowoff = ((size_t)(b * KD + oq)) * MM;
    Qbf[rowoff + mcol] = f2bf(acc[4][0][r] + bias);
    Qbf[rowoff + mcol + 16] = f2bf(acc[4][1][r] + bias);
  }
  __syncthreads();
  if (t < 64) {
    float m0_ = smax[0][t], m1_ = smax[1][t], m2_ = smax[2][t], m3_ = smax[3][t];
    float mm = fmaxf(fmaxf(m0_, m1_), fmaxf(m2_, m3_));
    float ss = ssum[0][t] * __expf(m0_ - mm) + ssum[1][t] * __expf(m1_ - mm) +
               ssum[2][t] * __expf(m2_ - mm) + ssum[3][t] * __expf(m3_ - mm);
    size_t po = ((size_t)blockIdx.x * 64 + t) * 2;
    pstat[po] = mm;
    pstat[po + 1] = ss;
  }
}

// ---- merge 32 per-block stats -> rmax, rsum (online-softmax merge) ----
__global__ __launch_bounds__(64) void k_pmerge(const float* __restrict__ pstat,
    float* __restrict__ rmax, float* __restrict__ rsum) {
  int b = blockIdx.x, o = threadIdx.x;
  float mm = -3.4e38f;
#pragma unroll 8
  for (int mc = 0; mc < 32; ++mc)
    mm = fmaxf(mm, pstat[((size_t)((b * 32 + mc) * 64 + o)) * 2]);
  float ss = 0.f;
#pragma unroll 8
  for (int mc = 0; mc < 32; ++mc) {
    size_t po = ((size_t)((b * 32 + mc) * 64 + o)) * 2;
    ss += pstat[po + 1] * __expf(pstat[po] - mm);
  }
  rmax[b * 64 + o] = mm;
  rsum[b * 64 + o] = ss;
}

// ---- BN affine params: 4 channels/block, coalesced row-streamed G ----
__global__ __launch_bounds__(256) void k_fin(const float* __restrict__ G,
    const float* __restrict__ xsump,
    const float* __restrict__ Wv, const float* __restrict__ bv,
    const float* __restrict__ gv, const float* __restrict__ btv,
    const float* __restrict__ Wq, const float* __restrict__ bq,
    const float* __restrict__ gq, const float* __restrict__ btq,
    float* __restrict__ AV, float* __restrict__ BVa,
    float* __restrict__ AQ, float* __restrict__ BQa) {
  int t = threadIdx.x, w = t >> 6, l = t & 63;
  int o0 = blockIdx.x * 4;
  __shared__ float lw[4][256];
#pragma unroll
  for (int oo = 0; oo < 4; ++oo) {
    int o = o0 + oo;
    lw[oo][t] = (o < 1024) ? Wv[(size_t)o * CC + t] : Wq[(size_t)(o - 1024) * CC + t];
  }
  __syncthreads();

  float4 w4[4];
#pragma unroll
  for (int oo = 0; oo < 4; ++oo) w4[oo] = *(const float4*)&lw[oo][4 * l];

  float qf[4] = {0.f, 0.f, 0.f, 0.f};
#pragma unroll 4
  for (int i = 0; i < 64; ++i) {
    int r = i * 4 + w;
    float4 g4 = *(const float4*)(G + (size_t)r * CC + 4 * l);
#pragma unroll
    for (int oo = 0; oo < 4; ++oo) {
      float d = g4.x * w4[oo].x + g4.y * w4[oo].y + g4.z * w4[oo].z + g4.w * w4[oo].w;
      qf[oo] = fmaf(lw[oo][r], d, qf[oo]);
    }
  }

  float xs = 0.f;
#pragma unroll
  for (int bb = 0; bb < 16; ++bb) xs += xsump[bb * 256 + t];
  float sx[4];
#pragma unroll
  for (int oo = 0; oo < 4; ++oo) sx[oo] = lw[oo][t] * xs;

#pragma unroll
  for (int oo = 0; oo < 4; ++oo)
#pragma unroll
    for (int od = 32; od; od >>= 1) {
      qf[oo] += __shfl_xor(qf[oo], od);
      sx[oo] += __shfl_xor(sx[oo], od);
    }
  __shared__ float rq[4][4], rs[4][4];
  if (l == 0)
#pragma unroll
    for (int oo = 0; oo < 4; ++oo) { rq[w][oo] = qf[oo]; rs[w][oo] = sx[oo]; }
  __syncthreads();
  if (t < 4) {
    int oo = t, o = o0 + oo;
    float q = rq[0][oo] + rq[1][oo] + rq[2][oo] + rq[3][oo];
    float s = rs[0][oo] + rs[1][oo] + rs[2][oo] + rs[3][oo];
    float bias, gamma, beta; float *pa, *pb;
    if (o < 1024) { bias = bv[o]; gamma = gv[o]; beta = btv[o]; pa = AV + o; pb = BVa + o; }
    else { int oi = o - 1024; bias = bq[oi]; gamma = gq[oi]; beta = btq[oi]; pa = AQ + oi; pb = BQa + oi; }
    const float invN = 1.f / 65536.f;
    float mean = s * invN + bias;
    float e2 = q * invN + 2.f * bias * s * invN + bias * bias;
    float var = e2 - mean * mean;
    float a = gamma * rsqrtf(var + EPSV);
    *pa = a;
    *pb = beta - mean * a;
  }
}

// ---- xp-partial = exp(K-rmax) . x^T  (dbuf LDS, one barrier per K-step) ----
__global__ __launch_bounds__(256) void k_xp(const unsigned short* __restrict__ xbf,
    const unsigned short* __restrict__ Kbf, const float* __restrict__ rmax,
    float* __restrict__ xpp) {
  int b = blockIdx.x >> 4, kc = blockIdx.x & 15;
  int kbase = kc * 256;
  __shared__ short la[2][64 * 40];
  __shared__ short lb[2][256 * 40];
  int t = threadIdx.x, w = t >> 6, l = t & 63;
  int lrow = l & 15, lk = (l >> 4) * 8;
  int ra = t >> 2, sga = (t & 3) * 8;    // A staging: row 0..63, seg 0..24

  float rm = rmax[b * UK + ra];
  const unsigned short* ksrc = Kbf + ((size_t)(b * UK + ra)) * MM + kbase + sga;
  const unsigned short* xsrc = xbf + ((size_t)(b * CC + ra)) * MM + kbase + sga;

  s16x8 kv, xv[4];

  // prologue: ks=0 loads + stage into buf 0
  kv = *(const s16x8*)ksrc;
#pragma unroll
  for (int i = 0; i < 4; ++i)
    xv[i] = *(const s16x8*)(xsrc + (size_t)i * 64 * MM);
  {
    s16x8 ev;
#pragma unroll
    for (int i = 0; i < 8; ++i)
      ev[i] = (short)f2bf(__expf(bfu((unsigned short)kv[i]) - rm));
    *(s16x8*)&la[0][ra * 40 + sga] = ev;
#pragma unroll
    for (int i = 0; i < 4; ++i)
      *(s16x8*)&lb[0][(ra + i * 64) * 40 + sga] = xv[i];
  }
  __syncthreads();

  f32x4 acc[4][4];
#pragma unroll
  for (int i = 0; i < 4; ++i)
#pragma unroll
    for (int j = 0; j < 4; ++j) acc[i][j] = (f32x4)0.f;

  for (int ks = 0; ks < 8; ++ks) {
    int buf = ks & 1;
    if (ks < 7) {   // issue next-step global loads early
      int k1 = (ks + 1) * 32;
      kv = *(const s16x8*)(ksrc + k1);
#pragma unroll
      for (int i = 0; i < 4; ++i)
        xv[i] = *(const s16x8*)(xsrc + (size_t)i * 64 * MM + k1);
    }
    s16x8 af[4], bfr[4];
#pragma unroll
    for (int i = 0; i < 4; ++i) af[i] = *(const s16x8*)&la[buf][(i * 16 + lrow) * 40 + lk];
#pragma unroll
    for (int j = 0; j < 4; ++j) bfr[j] = *(const s16x8*)&lb[buf][(w * 64 + j * 16 + lrow) * 40 + lk];
#pragma unroll
    for (int i = 0; i < 4; ++i)
#pragma unroll
      for (int j = 0; j < 4; ++j)
        acc[i][j] = __builtin_amdgcn_mfma_f32_16x16x32_bf16(af[i], bfr[j], acc[i][j], 0, 0, 0);
    if (ks < 7) {   // convert + write-late into the other buffer
      s16x8 ev;
#pragma unroll
      for (int i = 0; i < 8; ++i)
        ev[i] = (short)f2bf(__expf(bfu((unsigned short)kv[i]) - rm));
      *(s16x8*)&la[buf ^ 1][ra * 40 + sga] = ev;
#pragma unroll
      for (int i = 0; i < 4; ++i)
        *(s16x8*)&lb[buf ^ 1][(ra + i * 64) * 40 + sga] = xv[i];
    }
    __syncthreads();
  }

  float* dst = xpp + (size_t)blockIdx.x * UK * CC;
#pragma unroll
  for (int i = 0; i < 4; ++i)
#pragma unroll
    for (int j = 0; j < 4; ++j)
#pragma unroll
      for (int r = 0; r < 4; ++r) {
        int row = i * 16 + (l >> 4) * 4 + r;
        int col = w * 64 + j * 16 + lrow;
        dst[row * 256 + col] = acc[i][j][r];
      }
}

// ---- prep: xpn (reduce+normalize+bf16) and wvs (AV-scaled Wv, bf16), one launch ----
__global__ __launch_bounds__(256) void k_prep(const float* __restrict__ xpp,
    const float* __restrict__ rsum, const float* __restrict__ Wv,
    const float* __restrict__ AV, unsigned short* __restrict__ xpn,
    unsigned short* __restrict__ wvs) {
  int t = threadIdx.x;
  if (blockIdx.x < 256) {
    int b = blockIdx.x >> 4, kk = blockIdx.x & 15;
    unsigned short* dst = xpn + ((size_t)(b * 16 + kk)) * 1024;
#pragma unroll
    for (int u = 0; u < 4; ++u) {
      int row = u * 16 + kk;
      float s = 0.f;
#pragma unroll
      for (int kc = 0; kc < 16; ++kc)
        s += xpp[((size_t)(b * 16 + kc) * UK + row) * CC + t];
      s /= rsum[b * UK + row];
      dst[u * 256 + t] = f2bf(s);
    }
  } else {
    int ch = blockIdx.x - 256;   // 0..1023
    float a = AV[ch];
    wvs[(size_t)ch * CC + t] = f2bf(a * Wv[(size_t)ch * CC + t]);
  }
}

// ---- ctx[(b,kk)][vv] = xpn . wvs^T + cst[vv]  (MFMA, M=N=256, K=1024) ----
__global__ __launch_bounds__(64) void k_ctx2(const unsigned short* __restrict__ xpn,
    const unsigned short* __restrict__ wvs,
    const float* __restrict__ AV, const float* __restrict__ bv,
    const float* __restrict__ BVa, float* __restrict__ CTX) {
  int mt = blockIdx.x >> 3, nt = blockIdx.x & 7;
  int m0 = mt * 32, n0 = nt * 32;
  int l = threadIdx.x;
  int lrow = l & 15, lk8 = (l >> 4) * 8;

  f32x4 acc[2][2];
#pragma unroll
  for (int i = 0; i < 2; ++i)
#pragma unroll
    for (int j = 0; j < 2; ++j) acc[i][j] = (f32x4)0.f;

#pragma unroll 4
  for (int k0 = 0; k0 < 1024; k0 += 32) {
    int u = k0 >> 8, c0 = k0 & 255;
    s16x8 a0 = *(const s16x8*)&xpn[(size_t)(m0 + lrow) * 1024 + k0 + lk8];
    s16x8 a1 = *(const s16x8*)&xpn[(size_t)(m0 + 16 + lrow) * 1024 + k0 + lk8];
    s16x8 b0 = *(const s16x8*)&wvs[(size_t)(u * 256 + n0 + lrow) * CC + c0 + lk8];
    s16x8 b1 = *(const s16x8*)&wvs[(size_t)(u * 256 + n0 + 16 + lrow) * CC + c0 + lk8];
    acc[0][0] = __builtin_amdgcn_mfma_f32_16x16x32_bf16(a0, b0, acc[0][0], 0, 0, 0);
    acc[0][1] = __builtin_amdgcn_mfma_f32_16x16x32_bf16(a0, b1, acc[0][1], 0, 0, 0);
    acc[1][0] = __builtin_amdgcn_mfma_f32_16x16x32_bf16(a1, b0, acc[1][0], 0, 0, 0);
    acc[1][1] = __builtin_amdgcn_mfma_f32_16x16x32_bf16(a1, b1, acc[1][1], 0, 0, 0);
  }

  float cst[2];
#pragma unroll
  for (int j = 0; j < 2; ++j) {
    int vv = n0 + j * 16 + lrow;
    float s = 0.f;
#pragma unroll
    for (int u = 0; u < 4; ++u) {
      int ch = u * 256 + vv;
      s += AV[ch] * bv[ch] + BVa[ch];
    }
    cst[j] = s;
  }

#pragma unroll
  for (int i = 0; i < 2; ++i)
#pragma unroll
    for (int j = 0; j < 2; ++j)
#pragma unroll
      for (int r = 0; r < 4; ++r) {
        int row = m0 + i * 16 + (l >> 4) * 4 + r;
        int col = n0 + j * 16 + lrow;
        CTX[(size_t)row * 256 + col] = acc[i][j][r] + cst[j];
      }
}

// ---- y[b,vv,m] = sum_kk (aQ*Q+bQ)[kk,m] * ctx[kk,vv]  (bf16 Q input) ----
__global__ __launch_bounds__(256) void k_y(const unsigned short* __restrict__ Qbf,
    const float* __restrict__ CTX,
    const float* __restrict__ AQ, const float* __restrict__ BQa,
    float* __restrict__ y) {
  int b = blockIdx.x >> 4, nc = blockIdx.x & 15;
  int m = nc * 256 + threadIdx.x;
  float qn[16];
#pragma unroll
  for (int kk = 0; kk < 16; ++kk)
    qn[kk] = AQ[kk] * bfu(Qbf[((size_t)b * KD + kk) * MM + m]) + BQa[kk];
  const float* cb = CTX + (size_t)b * KD * 256;
  float* yo = y + (size_t)b * 256 * MM + m;
#pragma unroll 4
  for (int vv = 0; vv < 256; ++vv) {
    float acc = 0.f;
#pragma unroll
    for (int kk = 0; kk < 16; ++kk)
      acc = fmaf(qn[kk], cb[kk * 256 + vv], acc);
    yo[(size_t)vv * MM] = acc;
  }
}

extern "C" void kernel_launch(void* const* d_in, const int* in_sizes, int n_in,
                              void* d_out, int out_size, void* d_ws, size_t ws_size,
                              hipStream_t stream) {
  const float* x   = (const float*)d_in[0];
  const float* Wq  = (const float*)d_in[1];
  const float* bq  = (const float*)d_in[2];
  const float* Wk  = (const float*)d_in[3];
  const float* bk  = (const float*)d_in[4];
  const float* Wv  = (const float*)d_in[5];
  const float* bv  = (const float*)d_in[6];
  const float* gq  = (const float*)d_in[7];
  const float* btq = (const float*)d_in[8];
  const float* gv  = (const float*)d_in[9];
  const float* btv = (const float*)d_in[10];
  float* out = (float*)d_out;
  float* ws  = (float*)d_ws;

  // workspace layout (f32-element offsets) — no zero-init required anywhere
  float* G     = ws;                      // 65536     -> 65536
  float* XSUMP = ws + 65536;              // 4096      -> 69632
  float* PSTAT = ws + 69632;              // 65536     -> 135168 (512 blocks x 64 x 2)
  float* RMAX  = ws + 135168;             // 1024      -> 136192
  float* RSUM  = ws + 136192;             // 1024      -> 137216
  float* AV    = ws + 137216;             // 1024      -> 138240
  float* BVa   = ws + 138240;             // 1024      -> 139264
  float* AQ    = ws + 139264;             // 16        -> 139280
  float* BQa   = ws + 139280;             // 16 (pad)  -> 139520
  float* CTX   = ws + 139520;             // 65536     -> 205056
  u32*  PART   = (u32*)(ws + 205056);     // 8388608 u32 -> f32-elem 8593664 (dead after k_gred)
  float* XPP   = ws + 205056;             // 4194304   -> 4399360 (aliases PART)
  unsigned short* KBf = (unsigned short*)(ws + 4399360); // 4194304 bf16 -> 6496512 (aliases PART)
  unsigned short* QBf = (unsigned short*)(ws + 6496512); // 1048576 bf16 -> 7020800 (aliases PART)
  unsigned short* XBF = (unsigned short*)(ws + 8593664); // 16777216 bf16 -> 16982272
  unsigned short* XPN = (unsigned short*)(ws + 16982272); // 262144 bf16 -> 17113344
  unsigned short* WVS = (unsigned short*)(ws + 17113344); // 262144 bf16 -> 17244416 (~69 MB)

  k_cvt   <<<4096, 256, 0, stream>>>(x, XBF, XSUMP);
  k_gxx   <<<256,  512, 0, stream>>>(XBF, PART);
  k_gred  <<<128,  256, 0, stream>>>(PART, G);
  k_proj  <<<512,  256, 0, stream>>>(XBF, Wq, bq, Wk, bk, KBf, QBf, PSTAT);
  k_pmerge<<<16,   64,  0, stream>>>(PSTAT, RMAX, RSUM);
  k_fin   <<<260,  256, 0, stream>>>(G, XSUMP, Wv, bv, gv, btv, Wq, bq, gq, btq,
                                     AV, BVa, AQ, BQa);
  k_xp    <<<256,  256, 0, stream>>>(XBF, KBf, RMAX, XPP);
  k_prep  <<<1280, 256, 0, stream>>>(XPP, RSUM, Wv, AV, XPN, WVS);
  k_ctx2  <<<64,   64,  0, stream>>>(XPN, WVS, AV, bv, BVa, CTX);
  k_y     <<<256,  256, 0, stream>>>(QBf, CTX, AQ, BQa, out);
}